// Round 2
// baseline (264.536 us; speedup 1.0000x reference)
//
#include <hip/hip_runtime.h>

// Rotation by label: B=256, C=3, H=W=224 fp32.
//   lab 0: out[h][w] = in[h][w]
//   lab 1: out[h][w] = in[w][h]            (transpose)
//   lab 2: out[h][w] = in[223-h][w]        (flip rows)
//   lab 3: out[h][w] = in[223-w][h]        (transpose + flip cols)
//
// Band version: one block = one 32-row x 224-col output band of one (b,c)
// plane. Transpose path stages seven 32x32 source tiles into LDS (stride-33
// rows: <=2-way bank aliasing, free on wave64 per m136) with 7 loads in
// flight, ONE barrier, then 7 coalesced float4 row stores. Copy path is 7
// float4 copies/thread. Label tail fused as one extra block.

#define HW   224
#define TILE 32
#define NT   7      // 224/32
#define ROW4 56     // float4 per row

__global__ __launch_bounds__(256) void rot4_band(const float* __restrict__ x,
                                                 const int* __restrict__ label,
                                                 float* __restrict__ out,
                                                 int nimg_blocks, int B) {
    const int i = blockIdx.x;
    const int t = threadIdx.x;

    if (i >= nimg_blocks) {
        // label tail: out is read back as float32, so write float values
        const size_t img_elems = (size_t)B * 3 * HW * HW;
        if (t < B) out[img_elems + t] = (float)label[t];
        return;
    }

    int tmp = i;
    const int band = tmp % NT; tmp /= NT;   // output band index (rows h0..h0+31)
    const int c    = tmp % 3;  tmp /= 3;
    const int b    = tmp;

    const int lab = label[b];               // block-uniform -> no divergence
    const size_t plane = (size_t)(b * 3 + c) * (HW * HW);
    const float* __restrict__ in = x + plane;
    float* __restrict__ o = out + plane;

    const int h0 = band * TILE;

    if (lab == 0 || lab == 2) {
        // streaming copy, optional row flip; 1 KiB per wave per iter, coalesced
#pragma unroll
        for (int k = 0; k < NT; ++k) {
            const int idx = k * 256 + t;
            const int r   = idx / ROW4;     // 0..31
            const int c4  = idx % ROW4;     // 0..55
            const int orow = h0 + r;
            const int irow = (lab == 0) ? orow : (HW - 1 - orow);
            float4 v = *(const float4*)(in + (size_t)irow * HW + c4 * 4);
            *(float4*)(o + (size_t)orow * HW + c4 * 4) = v;
        }
    } else {
        // transpose band: 7 tiles in LDS, one barrier
        __shared__ float tb[NT][TILE][TILE + 1];   // 29568 B
        const int wl = t >> 3;                     // 0..31
        const int c4 = t & 7;                      // 0..7
#pragma unroll
        for (int k = 0; k < NT; ++k) {
            // source rows for output tile k: lab1 -> [32k,32k+32); lab3 -> [192-32k, 224-32k)
            const int rbase = (lab == 1) ? k * TILE : (HW - TILE - k * TILE);
            float4 v = *(const float4*)(in + (size_t)(rbase + wl) * HW + h0 + c4 * 4);
            tb[k][wl][c4 * 4 + 0] = v.x;
            tb[k][wl][c4 * 4 + 1] = v.y;
            tb[k][wl][c4 * 4 + 2] = v.z;
            tb[k][wl][c4 * 4 + 3] = v.w;
        }
        __syncthreads();
#pragma unroll
        for (int k = 0; k < NT; ++k) {
            float4 w;
            if (lab == 1) {
                // out[h0+wl][32k+4c4+j] = in[32k+4c4+j][h0+wl] = tb[k][4c4+j][wl]
                w.x = tb[k][c4 * 4 + 0][wl];
                w.y = tb[k][c4 * 4 + 1][wl];
                w.z = tb[k][c4 * 4 + 2][wl];
                w.w = tb[k][c4 * 4 + 3][wl];
            } else {
                // out[h0+wl][32k+4c4+j] = in[223-(32k+4c4+j)][h0+wl] = tb[k][31-(4c4+j)][wl]
                w.x = tb[k][31 - (c4 * 4 + 0)][wl];
                w.y = tb[k][31 - (c4 * 4 + 1)][wl];
                w.z = tb[k][31 - (c4 * 4 + 2)][wl];
                w.w = tb[k][31 - (c4 * 4 + 3)][wl];
            }
            *(float4*)(o + (size_t)(h0 + wl) * HW + k * TILE + c4 * 4) = w;
        }
    }
}

extern "C" void kernel_launch(void* const* d_in, const int* in_sizes, int n_in,
                              void* d_out, int out_size, void* d_ws, size_t ws_size,
                              hipStream_t stream) {
    const float* x     = (const float*)d_in[0];
    const int*   label = (const int*)d_in[1];
    float*       out   = (float*)d_out;

    const int B = in_sizes[1];                 // 256
    const int nimg_blocks = B * 3 * NT;        // one block per 32x224 band
    const int nblocks = nimg_blocks + 1;       // +1 block for the label tail

    rot4_band<<<nblocks, 256, 0, stream>>>(x, label, out, nimg_blocks, B);
}

// Round 3
// 262.333 us; speedup vs baseline: 1.0084x; 1.0084x over previous
//
#include <hip/hip_runtime.h>

// Rotation by label: B=256, C=3, H=W=224 fp32.
//   lab 0: out[h][w] = in[h][w]
//   lab 1: out[h][w] = in[w][h]            (transpose)
//   lab 2: out[h][w] = in[223-h][w]        (flip rows)
//   lab 3: out[h][w] = in[223-w][h]        (transpose + flip cols)
//
// Wave-private tile version: one WAVE owns one 32x32 tile. The transpose
// LDS tile is wave-private (tb[wave]), so no __syncthreads is needed --
// the compiler's own lgkmcnt wait orders the same-wave write->read. 4 waves
// per block -> 16.9 KB LDS -> 8 blocks/CU -> 32 waves/CU (100% occupancy).
// Each lane keeps 4 float4 loads in flight (explicit v[4] batch) for MLP.
// Stride-33 LDS rows -> <=2-way bank aliasing (free on wave64).

#define HW   224
#define TILE 32
#define NT   7      // 224/32

__global__ __launch_bounds__(256) void rot4_wave(const float* __restrict__ x,
                                                 const int* __restrict__ label,
                                                 float* __restrict__ out,
                                                 int nimg_blocks, int B) {
    const int t = threadIdx.x;

    if (blockIdx.x >= nimg_blocks) {
        // label tail: harness reads d_out as float32 -> write float values
        const size_t img_elems = (size_t)B * 3 * HW * HW;
        if (t < B) out[img_elems + t] = (float)label[t];
        return;
    }

    __shared__ float tb[4][TILE][TILE + 1];    // wave-private tiles, 16896 B

    const int wave = t >> 6;                   // 0..3
    const int lane = t & 63;

    int g = blockIdx.x * 4 + wave;             // global tile id
    const int tw = g % NT; g /= NT;            // tile col
    const int th = g % NT; g /= NT;            // tile row
    const int c  = g % 3;  g /= 3;             // channel
    const int b  = g;                          // batch

    const int lab = label[b];                  // wave-uniform
    const size_t plane = (size_t)(b * 3 + c) * (HW * HW);
    const float* __restrict__ in = x + plane;
    float* __restrict__ o = out + plane;

    const int h0 = th * TILE;
    const int w0 = tw * TILE;

    const int lr = lane >> 3;                  // 0..7 row-within-group
    const int c4 = lane & 7;                   // 0..7 float4 col

    if (lab == 0 || lab == 2) {
        // straight copy, optional row flip; 4 loads in flight, coalesced
        float4 v[4];
#pragma unroll
        for (int i = 0; i < 4; ++i) {
            const int r = i * 8 + lr;
            const int irow = (lab == 0) ? (h0 + r) : (HW - 1 - (h0 + r));
            v[i] = *(const float4*)(in + (size_t)irow * HW + w0 + c4 * 4);
        }
#pragma unroll
        for (int i = 0; i < 4; ++i) {
            const int r = i * 8 + lr;
            *(float4*)(o + (size_t)(h0 + r) * HW + w0 + c4 * 4) = v[i];
        }
    } else {
        // transpose via wave-private LDS tile -- no barrier
        // source rows: lab1 -> [w0, w0+32); lab3 -> [192-w0, 224-w0)
        const int rbase = (lab == 1) ? w0 : (HW - TILE - w0);
        float4 v[4];
#pragma unroll
        for (int i = 0; i < 4; ++i) {
            const int r = i * 8 + lr;
            v[i] = *(const float4*)(in + (size_t)(rbase + r) * HW + h0 + c4 * 4);
        }
#pragma unroll
        for (int i = 0; i < 4; ++i) {
            const int r = i * 8 + lr;
            tb[wave][r][c4 * 4 + 0] = v[i].x;
            tb[wave][r][c4 * 4 + 1] = v[i].y;
            tb[wave][r][c4 * 4 + 2] = v[i].z;
            tb[wave][r][c4 * 4 + 3] = v[i].w;
        }
        // same-wave write->read: compiler emits lgkmcnt wait; no __syncthreads
#pragma unroll
        for (int i = 0; i < 4; ++i) {
            const int r = i * 8 + lr;          // output row within tile
            float4 w;
            if (lab == 1) {
                // out[h0+r][w0+4c4+j] = in[w0+4c4+j][h0+r] = tb[4c4+j][r]
                w.x = tb[wave][c4 * 4 + 0][r];
                w.y = tb[wave][c4 * 4 + 1][r];
                w.z = tb[wave][c4 * 4 + 2][r];
                w.w = tb[wave][c4 * 4 + 3][r];
            } else {
                // out[h0+r][w0+4c4+j] = in[223-(w0+4c4+j)][h0+r] = tb[31-(4c4+j)][r]
                w.x = tb[wave][31 - (c4 * 4 + 0)][r];
                w.y = tb[wave][31 - (c4 * 4 + 1)][r];
                w.z = tb[wave][31 - (c4 * 4 + 2)][r];
                w.w = tb[wave][31 - (c4 * 4 + 3)][r];
            }
            *(float4*)(o + (size_t)(h0 + r) * HW + w0 + c4 * 4) = w;
        }
    }
}

extern "C" void kernel_launch(void* const* d_in, const int* in_sizes, int n_in,
                              void* d_out, int out_size, void* d_ws, size_t ws_size,
                              hipStream_t stream) {
    const float* x     = (const float*)d_in[0];
    const int*   label = (const int*)d_in[1];
    float*       out   = (float*)d_out;

    const int B = in_sizes[1];                     // 256
    const int ntiles = B * 3 * NT * NT;            // 37632
    const int nimg_blocks = ntiles / 4;            // 1 wave = 1 tile, 4 waves/block
    const int nblocks = nimg_blocks + 1;           // +1 for the label tail

    rot4_wave<<<nblocks, 256, 0, stream>>>(x, label, out, nimg_blocks, B);
}